// Round 15
// baseline (81.080 us; speedup 1.0000x reference)
//
#include <hip/hip_runtime.h>

#define TPB   256    // threads per block (4 waves)
#define QPT   8      // query points per thread (nn phase)
#define SPLIT 32     // database slices per direction
#define CPB   16     // query chunks per (dir,b) in reduce -> nred = 2*B*CPB
#define MAXRED 256   // max reducer partials supported
#define MAGIC 0x5AD00D5Au

typedef float f32x2 __attribute__((ext_vector_type(2)));

// ============================================================================
// ROUND 15: ONE graph node. R14 probe: nn = 9.8us, reduce ~3us -> R13's 31us
// is mostly node/launch overhead. Fuse via hand-rolled flag sync (NOT
// cooperative launch -- R11 spilled; NOT counters -- they need cross-node
// zeroing). nn blocks release nnflag[bid]=MAGIC after threadfence; 128
// reducer blocks acquire-spin on their (dir,b)'s 64 flags, reduce, release
// redflag; block 0 acquire-spins on redflags, combines fixed-order, writes
// out, then resets all flags for the next replay (safe: flags dead, kernel
// boundary publishes). MAGIC defeats the 0xAA first-replay poison. All 512
// blocks co-resident (2/CU, 8 waves/CU, ~8KB LDS) -> spins cannot deadlock.
// ============================================================================

__device__ __forceinline__ void block_reduce2(float& s, float& cc, float* red) {
    int tid = threadIdx.x;
    red[tid] = s;
    red[TPB + tid] = cc;
    __syncthreads();
    for (int o = TPB / 2; o > 0; o >>= 1) {
        if (tid < o) {
            red[tid]       += red[tid + o];
            red[TPB + tid] += red[TPB + tid + o];
        }
        __syncthreads();
    }
    s  = red[0];
    cc = red[TPB];
    __syncthreads();
}

__global__ void __launch_bounds__(TPB, 2) fused_kernel(
    const float* __restrict__ pred,
    const float* __restrict__ target,
    const int*   __restrict__ label,
    float* __restrict__ minsplit,          // [2][B][SPLIT][stride]
    float* __restrict__ pS, float* __restrict__ pC,   // [nred]
    unsigned int* __restrict__ nnflag,     // [gridDim.x]
    unsigned int* __restrict__ redflag,    // [nred]
    float* __restrict__ out,
    int B, int N, int M, int natmax, int stride)
{
    __shared__ float xs[TPB], ys[TPB], zs[TPB], ws[TPB];
    __shared__ float red[2 * TPB];

    const int bid = blockIdx.x;
    const int per_dir = B * natmax * SPLIT;

    // -------------------- phase 1: nn (all blocks) --------------------
    {
        const int dir = bid / per_dir;
        const int r1  = bid - dir * per_dir;
        const int b   = r1 / (natmax * SPLIT);
        const int r2  = r1 - b * (natmax * SPLIT);
        const int at  = r2 / SPLIT;
        const int sp  = r2 - at * SPLIT;

        const float* __restrict__ A  = dir ? target : pred;
        const float* __restrict__ Bp = dir ? pred   : target;
        const int NA = dir ? M : N;
        const int NB = dir ? N : M;
        const int* __restrict__ labB = dir ? label : nullptr;

        const int natiles = (NA + TPB * QPT - 1) / (TPB * QPT);
        if (at < natiles) {
            const size_t abase = (size_t)b * NA;

            float px[QPT], py[QPT], pz[QPT], pn[QPT];
            f32x2 best2[QPT];
#pragma unroll
            for (int q = 0; q < QPT; ++q) {
                int a = at * (TPB * QPT) + q * TPB + threadIdx.x;
                int idx = (a < NA) ? a : 0;
                const float* spq = A + (abase + idx) * 3;
                px[q] = spq[0];
                py[q] = spq[1];
                pz[q] = spq[2];
                pn[q] = fmaf(px[q], px[q], fmaf(py[q], py[q], pz[q] * pz[q]));
                best2[q] = (f32x2){3.0e38f, 3.0e38f};
            }

            const int slen = (NB + SPLIT - 1) / SPLIT;
            const int sbeg = sp * slen;
            const int send = min(sbeg + slen, NB);
            const size_t bbase = (size_t)b * NB;

            for (int c = sbeg; c < send; c += TPB) {
                const int cnt = min(send - c, TPB);
                if (threadIdx.x < cnt) {
                    int m = c + threadIdx.x;
                    const float* spm = Bp + (bbase + m) * 3;
                    float x = spm[0], y = spm[1], z = spm[2];
                    float tn = fmaf(x, x, fmaf(y, y, z * z));
                    if (labB != nullptr && labB[bbase + m] != 1) {  // invalid
                        x = 0.0f; y = 0.0f; z = 0.0f; tn = 1.0e10f;
                    }
                    xs[threadIdx.x] = -2.0f * x;
                    ys[threadIdx.x] = -2.0f * y;
                    zs[threadIdx.x] = -2.0f * z;
                    ws[threadIdx.x] = tn;
                }
                __syncthreads();

                const int npair = cnt >> 1;
#pragma unroll 4
                for (int jp = 0; jp < npair; ++jp) {
                    f32x2 tx = *reinterpret_cast<const f32x2*>(&xs[2 * jp]);
                    f32x2 ty = *reinterpret_cast<const f32x2*>(&ys[2 * jp]);
                    f32x2 tz = *reinterpret_cast<const f32x2*>(&zs[2 * jp]);
                    f32x2 tw = *reinterpret_cast<const f32x2*>(&ws[2 * jp]);
#pragma unroll
                    for (int q = 0; q < QPT; ++q) {
                        f32x2 vx = {px[q], px[q]};
                        f32x2 vy = {py[q], py[q]};
                        f32x2 vz = {pz[q], pz[q]};
                        f32x2 v = __builtin_elementwise_fma(vx, tx,
                                  __builtin_elementwise_fma(vy, ty,
                                  __builtin_elementwise_fma(vz, tz, tw)));
                        best2[q] = __builtin_elementwise_min(best2[q], v);
                    }
                }
                if (cnt & 1) {
                    float tx = xs[cnt - 1], ty = ys[cnt - 1];
                    float tz = zs[cnt - 1], tw = ws[cnt - 1];
#pragma unroll
                    for (int q = 0; q < QPT; ++q) {
                        float v = fmaf(px[q], tx, fmaf(py[q], ty, fmaf(pz[q], tz, tw)));
                        best2[q].x = fminf(best2[q].x, v);
                    }
                }
                __syncthreads();
            }

            float* o = minsplit + (((size_t)dir * B + b) * SPLIT + sp) * stride;
#pragma unroll
            for (int q = 0; q < QPT; ++q) {
                int a = at * (TPB * QPT) + q * TPB + threadIdx.x;
                if (a < NA) {
                    float best = fminf(best2[q].x, best2[q].y);
                    o[a] = fmaxf(best + pn[q], 0.0f);
                }
            }
        }
    }

    // release: this block's nn output is published
    __threadfence();
    if (threadIdx.x == 0) {
        atomicExch(&nnflag[bid], MAGIC);
    }

    // -------------------- phase 2: reduce (1 in rstride blocks) ---------
    const int rstride = (natmax * SPLIT) / CPB;       // 4 for 4x4096 shape
    const int nred = 2 * B * CPB;

    if ((bid % rstride) == 0) {
        const int rid = bid / rstride;                // [0, nred)
        const int dir = rid / (B * CPB);
        const int rem = rid - dir * (B * CPB);
        const int b   = rem / CPB;
        const int ch  = rem - b * CPB;
        const int NA  = dir ? M : N;

        // acquire: wait for the 64 nn blocks of (dir,b)
        const int fbase  = dir * per_dir + b * (natmax * SPLIT);
        const int nflags = natmax * SPLIT;
        for (int i = threadIdx.x; i < nflags; i += TPB) {
            while (__hip_atomic_load(&nnflag[fbase + i], __ATOMIC_ACQUIRE,
                                     __HIP_MEMORY_SCOPE_AGENT) != MAGIC) {
                __builtin_amdgcn_s_sleep(2);
            }
        }
        __syncthreads();

        const int qc  = (NA + CPB - 1) / CPB;         // queries per chunk
        const int qpt = (qc + TPB - 1) / TPB;
        const float* base = minsplit + ((size_t)(dir * B + b) * SPLIT) * stride;

        float s = 0.0f, cc = 0.0f;
        for (int k = 0; k < qpt; ++k) {
            int q = ch * qc + k * TPB + threadIdx.x;  // coalesced
            if (q < min((ch + 1) * qc, NA)) {
                float m = base[q];
#pragma unroll 8
                for (int sp = 1; sp < SPLIT; ++sp) {
                    m = fminf(m, base[(size_t)sp * stride + q]);
                }
                if (dir == 0) {
                    if (label[(size_t)b * N + q] == 1) { s += sqrtf(m); cc += 1.0f; }
                } else {
                    s += sqrtf(m);
                }
            }
        }

        block_reduce2(s, cc, red);

        if (threadIdx.x == 0) {
            pS[rid] = s;
            pC[rid] = cc;
            __threadfence();
            atomicExch(&redflag[rid], MAGIC);
        }
    }

    // -------------------- phase 3: combine + flag reset (block 0) -------
    if (bid == 0) {
        for (int i = threadIdx.x; i < nred; i += TPB) {
            while (__hip_atomic_load(&redflag[i], __ATOMIC_ACQUIRE,
                                     __HIP_MEMORY_SCOPE_AGENT) != MAGIC) {
                __builtin_amdgcn_s_sleep(2);
            }
        }
        __syncthreads();

        __shared__ float sS[MAXRED], sC[MAXRED];
        for (int i = threadIdx.x; i < nred; i += TPB) {
            sS[i] = atomicAdd(&pS[i], 0.0f);          // coherent parallel reads
            sC[i] = atomicAdd(&pC[i], 0.0f);
        }
        __syncthreads();

        if (threadIdx.x == 0) {
            float acc = 0.0f;
            for (int bb = 0; bb < B; ++bb) {
                float S1 = 0.0f, C1 = 0.0f, S2 = 0.0f;
                for (int i = 0; i < CPB; ++i) {
                    S1 += sS[bb * CPB + i];
                    C1 += sC[bb * CPB + i];
                    S2 += sS[B * CPB + bb * CPB + i];
                }
                float m1 = S1 / fmaxf(C1, 1.0f);
                float m2 = S2 / (float)M;
                acc += 0.5f * (m1 + m2);
            }
            out[0] = acc / (float)B;   // * LOSS_WEIGHT (== 1.0)
        }
        __syncthreads();

        // reset flags for the next graph replay (flags are dead now; the
        // kernel boundary publishes these plain stores)
        for (int i = threadIdx.x; i < 2 * per_dir; i += TPB) nnflag[i] = 0u;
        for (int i = threadIdx.x; i < nred; i += TPB)        redflag[i] = 0u;
    }
}

// ---------------------------------------------------------------------------
extern "C" void kernel_launch(void* const* d_in, const int* in_sizes, int n_in,
                              void* d_out, int out_size, void* d_ws, size_t ws_size,
                              hipStream_t stream) {
    const float* pred   = (const float*)d_in[0];  // B*N*3 f32
    const float* target = (const float*)d_in[1];  // B*M*3 f32
    const int*   label  = (const int*)  d_in[2];  // B*N   i32

    const int B = in_sizes[3];                 // nums has shape (B,)
    const int N = in_sizes[2] / B;             // label is B*N
    const int M = in_sizes[1] / (3 * B);       // target is B*M*3

    const int stride = (N > M) ? N : M;

    // workspace layout (~4.2 MiB of the provided scratch)
    float* minsplit = (float*)d_ws;                               // 2*B*SPLIT*stride
    const int nred = 2 * B * CPB;                                 // 128 partials
    float* pS = minsplit + (size_t)2 * B * SPLIT * stride;        // nred
    float* pC = pS + nred;                                        // nred
    unsigned int* nnflag  = (unsigned int*)(pC + nred);           // grid blocks
    const int nat1 = (N + TPB * QPT - 1) / (TPB * QPT);
    const int nat2 = (M + TPB * QPT - 1) / (TPB * QPT);
    const int natmax = (nat1 > nat2) ? nat1 : nat2;
    const int nblocks = 2 * B * natmax * SPLIT;                   // 512
    unsigned int* redflag = nnflag + nblocks;                     // nred

    fused_kernel<<<nblocks, TPB, 0, stream>>>(pred, target, label, minsplit,
                                              pS, pC, nnflag, redflag,
                                              (float*)d_out,
                                              B, N, M, natmax, stride);
}